// Round 4
// baseline (145.792 us; speedup 1.0000x reference)
//
#include <hip/hip_runtime.h>

// SoftMinLayer: sliding-window squared distance + softmin pooling.
// x: (512,1024) f32, sh: (100,50) f32 -> out (512,100) f32.
//
// R4 = R3 with the compile fix (__exp2f -> __builtin_amdgcn_exp2f).
// Structure: wave = (i,k), lane = 16-j tile.
//  - shapelet wave-uniform -> SGPRs (no per-lane 50-float array, no spill)
//  - x in LDS with +16B/16-float4 swizzle: 17 conflict-free ds_read_b128
//    of DISTINCT data per 800 FMAs (LDS pipe ~30%, was ~96%)
//  - ssq cancels exactly in Dm = D - min D -> dropped
//  - exact softmin: lane min(16) -> shfl_xor wave min -> 16 exp2 -> wave sums
//  - sq_win precomputed to d_ws (2 MB) by a prelim kernel; in-kernel fallback
//    if ws_size too small.

#define N_SEQ   512
#define Q_LEN   1024
#define K_SH    100
#define L_SH    50
#define J_WIN   974
#define ALPHA_F (-100.0f)
// exp(ALPHA*Dm) with Dm=(g-gm)/L, g unscaled: exp2(C2E*(g-gm)),
// C2E = ALPHA*log2(e)/L = -100 * 1.4426950408889634 / 50
#define C2E     (-2.8853900817779268f)

#define WS_ROW  1024            // ws row stride (floats); need 512*1024*4 = 2 MB
#define LX_F4   336             // swizzled x: logical F4 0..268 -> phys F+(F>>2) <= 335

// ---------- prelim: sq_win[i][j] = sum_{l<50} x[i][j+l]^2 -> ws ----------
__global__ __launch_bounds__(256)
void sqwin_kernel(const float* __restrict__ x, float* __restrict__ ws) {
    __shared__ __align__(16) float lds_x[Q_LEN];
    const int i = blockIdx.x, t = threadIdx.x;
    float4* lx4 = (float4*)lds_x;
    const float4* gx = (const float4*)(x + (size_t)i * Q_LEN);
    lx4[t] = gx[t];
    __syncthreads();
    if (t < 244) {   // j-group [4t, 4t+4)
        float s0 = 0.f, s1 = 0.f, s2 = 0.f, s3 = 0.f;
        #pragma unroll
        for (int q = 0; q < 14; ++q) {
            float4 v = (t + q < 256) ? lx4[t + q] : make_float4(0.f, 0.f, 0.f, 0.f);
            float xc[4] = {v.x, v.y, v.z, v.w};
            #pragma unroll
            for (int c = 0; c < 4; ++c) {
                const int p = 4 * q + c;
                const float x2 = xc[c] * xc[c];
                if (p >= 0 && p <= 49) s0 += x2;
                if (p >= 1 && p <= 50) s1 += x2;
                if (p >= 2 && p <= 51) s2 += x2;
                if (p >= 3 && p <= 52) s3 += x2;
            }
        }
        float4* w4 = (float4*)(ws + (size_t)i * WS_ROW);
        w4[t] = make_float4(s0, s1, s2, s3);
        if (t < 12) w4[244 + t] = make_float4(0.f, 0.f, 0.f, 0.f); // pad to 1024
    }
}

// ---------- main ----------
template<bool USE_WS>
__global__ __launch_bounds__(640, 4)
void softmin_main(const float* __restrict__ x, const float* __restrict__ sh,
                  float* __restrict__ out, const float* __restrict__ ws) {
    // x staged swizzled: logical float4 F at physical F + (F>>2).
    __shared__ __align__(16) float lds_x[LX_F4 * 4];
    __shared__ __align__(16) float lds_sq[WS_ROW];       // fallback only

    const int i    = blockIdx.x;
    const int tid  = threadIdx.x;
    const int lane = tid & 63;
    const int wave = tid >> 6;                 // 0..9
    const int k    = blockIdx.y * 10 + wave;   // < 100 always (grid.y = 10)

    // ---- shapelet row (wave-uniform; readfirstlane forces scalar addr) ----
    const int kw = __builtin_amdgcn_readfirstlane(k);
    const float* __restrict__ srow = sh + (size_t)kw * L_SH;
    float s[L_SH];
    #pragma unroll
    for (int l = 0; l < L_SH; ++l) s[l] = srow[l];

    // ---- stage x row swizzled ----
    {
        const float4* gx  = (const float4*)(x + (size_t)i * Q_LEN);
        float4*       lx4 = (float4*)lds_x;
        if (tid < 256) { const int t = tid; lx4[t + (t >> 2)] = gx[t]; }
    }

    // ---- fallback: compute sq_win into LDS from global x ----
    if (!USE_WS) {
        if (tid < 244) {
            const float4* gx = (const float4*)(x + (size_t)i * Q_LEN);
            float s0 = 0.f, s1 = 0.f, s2 = 0.f, s3 = 0.f;
            #pragma unroll
            for (int q = 0; q < 14; ++q) {
                float4 v = (tid + q < 256) ? gx[tid + q] : make_float4(0.f, 0.f, 0.f, 0.f);
                float xc[4] = {v.x, v.y, v.z, v.w};
                #pragma unroll
                for (int c = 0; c < 4; ++c) {
                    const int p = 4 * q + c;
                    const float x2 = xc[c] * xc[c];
                    if (p >= 0 && p <= 49) s0 += x2;
                    if (p >= 1 && p <= 50) s1 += x2;
                    if (p >= 2 && p <= 51) s2 += x2;
                    if (p >= 3 && p <= 52) s3 += x2;
                }
            }
            ((float4*)lds_sq)[tid] = make_float4(s0, s1, s2, s3);
        } else if (tid < 256) {
            ((float4*)lds_sq)[tid] = make_float4(0.f, 0.f, 0.f, 0.f);
        }
    }
    __syncthreads();

    // ---- FIR: lane covers j in [16*lane, 16*lane+16) ----
    float acc[16];
    #pragma unroll
    for (int d = 0; d < 16; ++d) acc[d] = 0.f;

    // lane's byte base: logical F = 4*lane+q -> phys byte 80*lane + 16*(q+(q>>2))
    const char* xbase = (const char*)lds_x + 80 * lane;
    #pragma unroll
    for (int q = 0; q < 17; ++q) {
        const float4 xv = *(const float4*)(xbase + 16 * (q + (q >> 2)));
        const float xc[4] = {xv.x, xv.y, xv.z, xv.w};
        #pragma unroll
        for (int c = 0; c < 4; ++c) {
            const int p = 4 * q + c;      // x offset within lane window [0,68)
            #pragma unroll
            for (int d = 0; d < 16; ++d) {
                const int l = p - d;
                if (l >= 0 && l < L_SH)
                    acc[d] = fmaf(xc[c], s[l], acc[d]);
            }
        }
    }

    // ---- g[d] = sq_win - 2*acc (unscaled distance*L; ssq cancels in Dm) ----
    float g[16];
    if (USE_WS) {
        const float4* w4 = (const float4*)(ws + (size_t)i * WS_ROW) + 4 * lane;
        #pragma unroll
        for (int d4 = 0; d4 < 4; ++d4) {
            const float4 sq = w4[d4];
            g[4 * d4 + 0] = fmaf(-2.f, acc[4 * d4 + 0], sq.x);
            g[4 * d4 + 1] = fmaf(-2.f, acc[4 * d4 + 1], sq.y);
            g[4 * d4 + 2] = fmaf(-2.f, acc[4 * d4 + 2], sq.z);
            g[4 * d4 + 3] = fmaf(-2.f, acc[4 * d4 + 3], sq.w);
        }
    } else {
        const float4* w4 = (const float4*)lds_sq + 4 * lane;
        #pragma unroll
        for (int d4 = 0; d4 < 4; ++d4) {
            const float4 sq = w4[d4];
            g[4 * d4 + 0] = fmaf(-2.f, acc[4 * d4 + 0], sq.x);
            g[4 * d4 + 1] = fmaf(-2.f, acc[4 * d4 + 1], sq.y);
            g[4 * d4 + 2] = fmaf(-2.f, acc[4 * d4 + 2], sq.z);
            g[4 * d4 + 3] = fmaf(-2.f, acc[4 * d4 + 3], sq.w);
        }
    }

    // ---- mask invalid j, exact wave min ----
    const int j0 = 16 * lane;
    #pragma unroll
    for (int d = 0; d < 16; ++d)
        if (j0 + d >= J_WIN) g[d] = 3.0e38f;

    float gm = g[0];
    #pragma unroll
    for (int d = 1; d < 16; ++d) gm = fminf(gm, g[d]);
    #pragma unroll
    for (int off = 1; off < 64; off <<= 1)
        gm = fminf(gm, __shfl_xor(gm, off, 64));

    // ---- softmin sums ----
    float S = 0.f, T = 0.f;
    #pragma unroll
    for (int d = 0; d < 16; ++d) {
        const float t = g[d] - gm;                 // >= 0; invalid: huge -> w=0
        const float w = __builtin_amdgcn_exp2f(C2E * t);   // exp(ALPHA*t/L)
        S += w;
        T = fmaf(t, w, T);
    }
    #pragma unroll
    for (int off = 1; off < 64; off <<= 1) {
        S += __shfl_xor(S, off, 64);
        T += __shfl_xor(T, off, 64);
    }

    if (lane == 0)
        out[(size_t)i * K_SH + k] = (T / S) * (1.f / (float)L_SH);
}

extern "C" void kernel_launch(void* const* d_in, const int* in_sizes, int n_in,
                              void* d_out, int out_size, void* d_ws, size_t ws_size,
                              hipStream_t stream) {
    const float* x  = (const float*)d_in[0];   // (512, 1024) f32
    const float* sh = (const float*)d_in[1];   // (100, 50)  f32
    float* out = (float*)d_out;                // (512, 100) f32
    float* ws  = (float*)d_ws;

    const bool use_ws = ws_size >= (size_t)N_SEQ * WS_ROW * sizeof(float); // 2 MB
    dim3 grid(N_SEQ, 10);
    if (use_ws) {
        sqwin_kernel<<<N_SEQ, 256, 0, stream>>>(x, ws);
        softmin_main<true><<<grid, 640, 0, stream>>>(x, sh, out, ws);
    } else {
        softmin_main<false><<<grid, 640, 0, stream>>>(x, sh, out, nullptr);
    }
}